// Round 1
// baseline (646.847 us; speedup 1.0000x reference)
//
#include <hip/hip_runtime.h>
#include <math.h>

#define CCH 128   // channels
#define WIN 5
#define HALFW 2

// Precompute M = W^T W (symmetric, 128x128) and v = W^T b into workspace.
// Grid: CCH+1 blocks x CCH threads. Block c<CCH computes row M[c][*]; block CCH computes v.
__global__ __launch_bounds__(CCH) void fr_precompute(const float* __restrict__ pw,
                                                     const float* __restrict__ pb,
                                                     float* __restrict__ Mv) {
    const int c = blockIdx.x;
    const int t = threadIdx.x;
    float s = 0.f;
    if (c < CCH) {
        #pragma unroll 4
        for (int o = 0; o < CCH; ++o) s = fmaf(pw[o * CCH + c], pw[o * CCH + t], s);
        Mv[c * CCH + t] = s;
    } else {
        #pragma unroll 4
        for (int o = 0; o < CCH; ++o) s = fmaf(pb[o], pw[o * CCH + t], s);
        Mv[CCH * CCH + t] = s;
    }
}

// One block (128 threads, thread==channel) per point.
__global__ __launch_bounds__(CCH) void fr_refine(
    const float* __restrict__ mk0, const float* __restrict__ mk1,
    const float* __restrict__ feat0, const float* __restrict__ feat1,
    const float* __restrict__ Mv, const int* __restrict__ stride_p,
    float* __restrict__ out, int N, int H, int W) {

    const int n = blockIdx.x;
    const int t = threadIdx.x;
    const long HW = (long)H * W;

    const int stride = *stride_p;          // 8
    const int fine_ratio = stride >> 1;    // 4
    const float frf = (float)fine_ratio;
    const float scale = (float)(stride / fine_ratio);   // 2
    const float half_s = (float)(stride >> 1);          // 4

    const float m0x = mk0[2 * n], m0y = mk0[2 * n + 1];
    const float m1x = mk1[2 * n], m1y = mk1[2 * n + 1];

    const int cx0 = (int)(m0x * frf), cy0 = (int)(m0y * frf);
    const int cx1 = (int)(m1x * frf), cy1 = (int)(m1y * frf);

    const bool valid =
        (cx0 >= HALFW) && (cx0 + HALFW < W) && (cy0 >= HALFW) && (cy0 + HALFW < H) &&
        (cx1 >= HALFW) && (cx1 + HALFW < W) && (cy1 >= HALFW) && (cy1 + HALFW < H);

    const int cx0c = min(max(cx0, HALFW), W - 1 - HALFW);
    const int cy0c = min(max(cy0, HALFW), H - 1 - HALFW);
    const int cx1c = min(max(cx1, HALFW), W - 1 - HALFW);
    const int cy1c = min(max(cy1, HALFW), H - 1 - HALFW);

    __shared__ float sh_x0[CCH];
    __shared__ float red[2 * 25];

    // Gather center column of feat0 (one scattered 4B load per channel).
    sh_x0[t] = feat0[(long)t * HW + (long)cy0c * W + cx0c];
    __syncthreads();

    // g[t] = v[t] + sum_c M[c][t] * x0[c]   (M symmetric; [c][t] order => coalesced)
    float g = Mv[CCH * CCH + t];
    #pragma unroll 8
    for (int c = 0; c < CCH; ++c) {
        g = fmaf(Mv[c * CCH + t], sh_x0[c], g);
    }

    // Per-channel contribution to the 25 correlations.
    const float* f1b = feat1 + (long)t * HW + (long)(cy1c - HALFW) * W + (cx1c - HALFW);
    float prod[25];
    #pragma unroll
    for (int dy = 0; dy < WIN; ++dy) {
        #pragma unroll
        for (int dx = 0; dx < WIN; ++dx) {
            prod[dy * WIN + dx] = g * f1b[(long)dy * W + dx];
        }
    }

    // Reduce each of the 25 values across the 128 threads (2 waves).
    const int lane = t & 63;
    const int wv = t >> 6;
    #pragma unroll
    for (int j = 0; j < 25; ++j) {
        float v = prod[j];
        v += __shfl_down(v, 32);
        v += __shfl_down(v, 16);
        v += __shfl_down(v, 8);
        v += __shfl_down(v, 4);
        v += __shfl_down(v, 2);
        v += __shfl_down(v, 1);
        if (lane == 0) red[wv * 25 + j] = v;
    }
    __syncthreads();

    if (t == 0) {
        float corr[25];
        float mx = -1e30f;
        #pragma unroll
        for (int j = 0; j < 25; ++j) {
            corr[j] = red[j] + red[25 + j];
            mx = fmaxf(mx, corr[j]);
        }
        float sum = 0.f;
        #pragma unroll
        for (int j = 0; j < 25; ++j) {
            float e = __expf(corr[j] - mx);
            corr[j] = e;
            sum += e;
        }
        const float inv = 1.f / sum;
        float ox = 0.f, oy = 0.f;
        #pragma unroll
        for (int j = 0; j < 25; ++j) {
            const float w = corr[j] * inv;
            ox += w * (float)(j % WIN - HALFW);
            oy += w * (float)(j / WIN - HALFW);
        }
        if (!valid) { ox = 0.f; oy = 0.f; }
        const float sf = (float)stride;
        out[2 * N + 2 * n]     = m1x * sf + half_s + ox * scale;
        out[2 * N + 2 * n + 1] = m1y * sf + half_s + oy * scale;
        out[2 * n]     = m0x * sf + half_s;
        out[2 * n + 1] = m0y * sf + half_s;
    }
}

extern "C" void kernel_launch(void* const* d_in, const int* in_sizes, int n_in,
                              void* d_out, int out_size, void* d_ws, size_t ws_size,
                              hipStream_t stream) {
    const float* mk0 = (const float*)d_in[0];
    const float* mk1 = (const float*)d_in[1];
    const float* f0  = (const float*)d_in[2];
    const float* f1  = (const float*)d_in[3];
    const float* pw  = (const float*)d_in[4];
    const float* pb  = (const float*)d_in[5];
    const int*   sp  = (const int*)d_in[6];

    const int N = in_sizes[0] / 2;              // 20000
    const long HW = (long)in_sizes[2] / CCH;    // 409600
    const int Wf = (int)(sqrt((double)HW) + 0.5);
    const int Hf = (int)(HW / Wf);

    float* Mv = (float*)d_ws;                   // 128*128 + 128 floats

    fr_precompute<<<CCH + 1, CCH, 0, stream>>>(pw, pb, Mv);
    fr_refine<<<N, CCH, 0, stream>>>(mk0, mk1, f0, f1, Mv, sp, (float*)d_out, N, Hf, Wf);
}

// Round 2
// 543.906 us; speedup vs baseline: 1.1893x; 1.1893x over previous
//
#include <hip/hip_runtime.h>
#include <math.h>

#define CCH 128   // channels
#define WIN 5
#define HALFW 2

// Precompute M = W^T W (symmetric, 128x128) and v = W^T b into workspace.
__global__ __launch_bounds__(CCH) void fr_precompute(const float* __restrict__ pw,
                                                     const float* __restrict__ pb,
                                                     float* __restrict__ Mv) {
    const int c = blockIdx.x;
    const int t = threadIdx.x;
    float s = 0.f;
    if (c < CCH) {
        #pragma unroll 4
        for (int o = 0; o < CCH; ++o) s = fmaf(pw[o * CCH + c], pw[o * CCH + t], s);
        Mv[c * CCH + t] = s;
    } else {
        #pragma unroll 4
        for (int o = 0; o < CCH; ++o) s = fmaf(pb[o], pw[o * CCH + t], s);
        Mv[CCH * CCH + t] = s;
    }
}

// Transpose feat1 [C][HW] -> ft [HW][C]. 64 pixels per block, 256 threads.
// LDS tile padded to stride 129 -> conflict-free both phases.
__global__ __launch_bounds__(256) void fr_transpose(const float* __restrict__ feat1,
                                                    float* __restrict__ ft,
                                                    long HW) {
    __shared__ float lds[64 * 129];
    const long pix0 = (long)blockIdx.x * 64;
    const int tid = threadIdx.x;

    // Read: 32 iters, each wave reads 64 consecutive pixels of one channel (256B).
    const int p = tid & 63;
    const int csub = tid >> 6;          // 0..3
    #pragma unroll 8
    for (int it = 0; it < 32; ++it) {
        const int c = it * 4 + csub;
        lds[p * 129 + c] = feat1[(long)c * HW + pix0 + p];
    }
    __syncthreads();

    // Write: 32 iters, each wave writes 64 consecutive channels of one pixel (256B).
    const int c2 = tid & 127;
    const int psub = tid >> 7;          // 0..1
    #pragma unroll 8
    for (int it = 0; it < 32; ++it) {
        const int pp = it * 2 + psub;
        ft[(pix0 + pp) * CCH + c2] = lds[pp * 129 + c2];
    }
}

// One block (128 threads, thread==channel) per point.
template <bool USE_FT>
__global__ __launch_bounds__(CCH) void fr_refine(
    const float* __restrict__ mk0, const float* __restrict__ mk1,
    const float* __restrict__ feat0, const float* __restrict__ feat1,
    const float* __restrict__ ft,   // [HW][C] transposed feat1 (USE_FT path)
    const float* __restrict__ Mv, const int* __restrict__ stride_p,
    float* __restrict__ out, int N, int H, int W) {

    const int n = blockIdx.x;
    const int t = threadIdx.x;
    const long HW = (long)H * W;

    const int stride = *stride_p;          // 8
    const int fine_ratio = stride >> 1;    // 4
    const float frf = (float)fine_ratio;
    const float scale = (float)(stride / fine_ratio);   // 2
    const float half_s = (float)(stride >> 1);          // 4

    const float m0x = mk0[2 * n], m0y = mk0[2 * n + 1];
    const float m1x = mk1[2 * n], m1y = mk1[2 * n + 1];

    const int cx0 = (int)(m0x * frf), cy0 = (int)(m0y * frf);
    const int cx1 = (int)(m1x * frf), cy1 = (int)(m1y * frf);

    const bool valid =
        (cx0 >= HALFW) && (cx0 + HALFW < W) && (cy0 >= HALFW) && (cy0 + HALFW < H) &&
        (cx1 >= HALFW) && (cx1 + HALFW < W) && (cy1 >= HALFW) && (cy1 + HALFW < H);

    const int cx0c = min(max(cx0, HALFW), W - 1 - HALFW);
    const int cy0c = min(max(cy0, HALFW), H - 1 - HALFW);
    const int cx1c = min(max(cx1, HALFW), W - 1 - HALFW);
    const int cy1c = min(max(cy1, HALFW), H - 1 - HALFW);

    __shared__ float sh_x0[CCH];
    __shared__ float red[2 * 25];

    // Gather center column of feat0 (one scattered 4B load per channel).
    sh_x0[t] = feat0[(long)t * HW + (long)cy0c * W + cx0c];
    __syncthreads();

    // g[t] = v[t] + sum_c M[c][t] * x0[c]   (coalesced column reads of symmetric M)
    float g = Mv[CCH * CCH + t];
    #pragma unroll 8
    for (int c = 0; c < CCH; ++c) {
        g = fmaf(Mv[c * CCH + t], sh_x0[c], g);
    }

    // Per-channel contribution to the 25 correlations.
    float prod[25];
    if (USE_FT) {
        const long pbase = (long)(cy1c - HALFW) * W + (cx1c - HALFW);
        #pragma unroll
        for (int dy = 0; dy < WIN; ++dy) {
            #pragma unroll
            for (int dx = 0; dx < WIN; ++dx) {
                const long pix = pbase + (long)dy * W + dx;
                prod[dy * WIN + dx] = g * ft[pix * CCH + t];
            }
        }
    } else {
        const float* f1b = feat1 + (long)t * HW + (long)(cy1c - HALFW) * W + (cx1c - HALFW);
        #pragma unroll
        for (int dy = 0; dy < WIN; ++dy) {
            #pragma unroll
            for (int dx = 0; dx < WIN; ++dx) {
                prod[dy * WIN + dx] = g * f1b[(long)dy * W + dx];
            }
        }
    }

    // Reduce each of the 25 values across the 128 threads (2 waves).
    const int lane = t & 63;
    const int wv = t >> 6;
    #pragma unroll
    for (int j = 0; j < 25; ++j) {
        float v = prod[j];
        v += __shfl_down(v, 32);
        v += __shfl_down(v, 16);
        v += __shfl_down(v, 8);
        v += __shfl_down(v, 4);
        v += __shfl_down(v, 2);
        v += __shfl_down(v, 1);
        if (lane == 0) red[wv * 25 + j] = v;
    }
    __syncthreads();

    if (t == 0) {
        float corr[25];
        float mx = -1e30f;
        #pragma unroll
        for (int j = 0; j < 25; ++j) {
            corr[j] = red[j] + red[25 + j];
            mx = fmaxf(mx, corr[j]);
        }
        float sum = 0.f;
        #pragma unroll
        for (int j = 0; j < 25; ++j) {
            float e = __expf(corr[j] - mx);
            corr[j] = e;
            sum += e;
        }
        const float inv = 1.f / sum;
        float ox = 0.f, oy = 0.f;
        #pragma unroll
        for (int j = 0; j < 25; ++j) {
            const float w = corr[j] * inv;
            ox += w * (float)(j % WIN - HALFW);
            oy += w * (float)(j / WIN - HALFW);
        }
        if (!valid) { ox = 0.f; oy = 0.f; }
        const float sf = (float)stride;
        out[2 * N + 2 * n]     = m1x * sf + half_s + ox * scale;
        out[2 * N + 2 * n + 1] = m1y * sf + half_s + oy * scale;
        out[2 * n]     = m0x * sf + half_s;
        out[2 * n + 1] = m0y * sf + half_s;
    }
}

extern "C" void kernel_launch(void* const* d_in, const int* in_sizes, int n_in,
                              void* d_out, int out_size, void* d_ws, size_t ws_size,
                              hipStream_t stream) {
    const float* mk0 = (const float*)d_in[0];
    const float* mk1 = (const float*)d_in[1];
    const float* f0  = (const float*)d_in[2];
    const float* f1  = (const float*)d_in[3];
    const float* pw  = (const float*)d_in[4];
    const float* pb  = (const float*)d_in[5];
    const int*   sp  = (const int*)d_in[6];

    const int N = in_sizes[0] / 2;              // 20000
    const long HW = (long)in_sizes[2] / CCH;    // 409600
    const int Wf = (int)(sqrt((double)HW) + 0.5);
    const int Hf = (int)(HW / Wf);

    const size_t ft_bytes = (size_t)HW * CCH * sizeof(float);       // ~210 MB
    const size_t mv_bytes = (size_t)(CCH * CCH + CCH) * sizeof(float);
    const bool use_ft = (ws_size >= ft_bytes + mv_bytes);

    float* ft = (float*)d_ws;                       // [HW][C]
    float* Mv = use_ft ? (float*)((char*)d_ws + ft_bytes) : (float*)d_ws;

    fr_precompute<<<CCH + 1, CCH, 0, stream>>>(pw, pb, Mv);

    if (use_ft) {
        fr_transpose<<<(int)(HW / 64), 256, 0, stream>>>(f1, ft, HW);
        fr_refine<true><<<N, CCH, 0, stream>>>(mk0, mk1, f0, f1, ft, Mv, sp,
                                               (float*)d_out, N, Hf, Wf);
    } else {
        fr_refine<false><<<N, CCH, 0, stream>>>(mk0, mk1, f0, f1, nullptr, Mv, sp,
                                                (float*)d_out, N, Hf, Wf);
    }
}

// Round 3
// 495.593 us; speedup vs baseline: 1.3052x; 1.0975x over previous
//
#include <hip/hip_runtime.h>
#include <math.h>

#define CCH 128
#define WIN 5
#define HALFW 2
#define TP 131   // fp32 LDS pad for transpose (2-way write / 4-way read conflicts only)

__device__ __forceinline__ unsigned short f2bf(float f) {
    unsigned int b = __float_as_uint(f);
    b += 0x7FFFu + ((b >> 16) & 1u);       // round-to-nearest-even
    return (unsigned short)(b >> 16);
}
__device__ __forceinline__ float bf2f(unsigned short u) {
    return __uint_as_float(((unsigned int)u) << 16);
}

// M = W^T W (128x128) and v = W^T b into workspace.
__global__ __launch_bounds__(CCH) void fr_precompute(const float* __restrict__ pw,
                                                     const float* __restrict__ pb,
                                                     float* __restrict__ Mv) {
    const int c = blockIdx.x;
    const int t = threadIdx.x;
    float s = 0.f;
    if (c < CCH) {
        #pragma unroll 4
        for (int o = 0; o < CCH; ++o) s = fmaf(pw[o * CCH + c], pw[o * CCH + t], s);
        Mv[c * CCH + t] = s;
    } else {
        #pragma unroll 4
        for (int o = 0; o < CCH; ++o) s = fmaf(pb[o], pw[o * CCH + t], s);
        Mv[CCH * CCH + t] = s;
    }
}

// feat1 [C][HW] fp32 -> ft [HW][C] bf16. 64 pixels/block, 256 threads.
__global__ __launch_bounds__(256) void fr_transpose_bf16(const float* __restrict__ feat1,
                                                         unsigned short* __restrict__ ft,
                                                         long HW) {
    __shared__ float lds[64 * TP];
    const long pix0 = (long)blockIdx.x * 64;
    const int tid = threadIdx.x;

    // Read: thread = (channel group, 4-pixel group). float4 global loads.
    {
        const int s16 = tid & 15;          // 4-pixel group: pixels s16*4..+3
        const int grp = tid >> 4;          // channel sub-index
        #pragma unroll
        for (int it = 0; it < 8; ++it) {
            const int c = grp + it * 16;
            const float4 v = *(const float4*)&feat1[(long)c * HW + pix0 + s16 * 4];
            lds[(s16 * 4 + 0) * TP + c] = v.x;
            lds[(s16 * 4 + 1) * TP + c] = v.y;
            lds[(s16 * 4 + 2) * TP + c] = v.z;
            lds[(s16 * 4 + 3) * TP + c] = v.w;
        }
    }
    __syncthreads();

    // Write: thread = (pixel, 4-channel group). 8B packed bf16 stores.
    {
        const int cq = tid & 31;           // channels cq*4..+3
        const int pq = tid >> 5;           // 0..7
        #pragma unroll
        for (int it = 0; it < 8; ++it) {
            const int pp = pq + it * 8;
            const float* row = &lds[pp * TP + cq * 4];
            ushort4 o;
            o.x = f2bf(row[0]); o.y = f2bf(row[1]);
            o.z = f2bf(row[2]); o.w = f2bf(row[3]);
            *(ushort4*)&ft[((pix0 + pp) * CCH) + cq * 4] = o;
        }
    }
}

// 32 lanes per point, 4 channels per lane. 8 points per 256-thread block.
__global__ __launch_bounds__(256) void fr_refine2(
    const float* __restrict__ mk0, const float* __restrict__ mk1,
    const float* __restrict__ feat0, const unsigned short* __restrict__ ft,
    const float* __restrict__ Mv, const int* __restrict__ stride_p,
    float* __restrict__ out, int N, int H, int W) {

    const int tid = threadIdx.x;
    const int pt  = tid >> 5;          // point within block (0..7)
    const int sub = tid & 31;          // lane within point
    const int n   = blockIdx.x * 8 + pt;
    const int nn  = (n < N) ? n : 0;
    const long HW = (long)H * W;

    const int stride = *stride_p;            // 8
    const int fine_ratio = stride >> 1;      // 4
    const float frf = (float)fine_ratio;
    const float scale = (float)(stride / fine_ratio);
    const float half_s = (float)(stride >> 1);

    const float2 m0 = *(const float2*)&mk0[2 * nn];
    const float2 m1 = *(const float2*)&mk1[2 * nn];

    const int cx0 = (int)(m0.x * frf), cy0 = (int)(m0.y * frf);
    const int cx1 = (int)(m1.x * frf), cy1 = (int)(m1.y * frf);

    const bool valid =
        (cx0 >= HALFW) && (cx0 + HALFW < W) && (cy0 >= HALFW) && (cy0 + HALFW < H) &&
        (cx1 >= HALFW) && (cx1 + HALFW < W) && (cy1 >= HALFW) && (cy1 + HALFW < H);

    const int cx0c = min(max(cx0, HALFW), W - 1 - HALFW);
    const int cy0c = min(max(cy0, HALFW), H - 1 - HALFW);
    const int cx1c = min(max(cx1, HALFW), W - 1 - HALFW);
    const int cy1c = min(max(cy1, HALFW), H - 1 - HALFW);

    __shared__ float sh_x0[8][CCH];

    // Gather 4 channels of the feat0 center column (4 scattered loads/lane).
    {
        const long off0 = (long)cy0c * W + cx0c;
        float4 x0v;
        x0v.x = feat0[(long)(4 * sub + 0) * HW + off0];
        x0v.y = feat0[(long)(4 * sub + 1) * HW + off0];
        x0v.z = feat0[(long)(4 * sub + 2) * HW + off0];
        x0v.w = feat0[(long)(4 * sub + 3) * HW + off0];
        *(float4*)&sh_x0[pt][4 * sub] = x0v;
    }
    __syncthreads();

    // g[j] = v[4sub+j] + sum_c M[c][4sub+j] * x0[c]  — float4 Mv loads.
    float4 g = *(const float4*)&Mv[CCH * CCH + 4 * sub];
    {
        const float4* shx = (const float4*)sh_x0[pt];
        #pragma unroll 8
        for (int c4 = 0; c4 < 32; ++c4) {
            const float4 xv = shx[c4];
            const float4 r0 = *(const float4*)&Mv[(c4 * 4 + 0) * CCH + 4 * sub];
            const float4 r1 = *(const float4*)&Mv[(c4 * 4 + 1) * CCH + 4 * sub];
            const float4 r2 = *(const float4*)&Mv[(c4 * 4 + 2) * CCH + 4 * sub];
            const float4 r3 = *(const float4*)&Mv[(c4 * 4 + 3) * CCH + 4 * sub];
            g.x = fmaf(r0.x, xv.x, g.x); g.y = fmaf(r0.y, xv.x, g.y);
            g.z = fmaf(r0.z, xv.x, g.z); g.w = fmaf(r0.w, xv.x, g.w);
            g.x = fmaf(r1.x, xv.y, g.x); g.y = fmaf(r1.y, xv.y, g.y);
            g.z = fmaf(r1.z, xv.y, g.z); g.w = fmaf(r1.w, xv.y, g.w);
            g.x = fmaf(r2.x, xv.z, g.x); g.y = fmaf(r2.y, xv.z, g.y);
            g.z = fmaf(r2.z, xv.z, g.z); g.w = fmaf(r2.w, xv.z, g.w);
            g.x = fmaf(r3.x, xv.w, g.x); g.y = fmaf(r3.y, xv.w, g.y);
            g.z = fmaf(r3.z, xv.w, g.z); g.w = fmaf(r3.w, xv.w, g.w);
        }
    }

    // 25 taps: one ushort4 (4 bf16 channels) load per lane per tap.
    ushort4 u[25];
    {
        const long pbase = (long)(cy1c - HALFW) * W + (cx1c - HALFW);
        #pragma unroll
        for (int dy = 0; dy < WIN; ++dy) {
            #pragma unroll
            for (int dx = 0; dx < WIN; ++dx) {
                const long pix = pbase + (long)dy * W + dx;
                u[dy * WIN + dx] = *(const ushort4*)&ft[pix * CCH + 4 * sub];
            }
        }
    }

    // Dot + width-32 shuffle reduce. Lane sub==0 ends with all 25 corr values.
    float corr[25];
    #pragma unroll
    for (int j = 0; j < 25; ++j) {
        float v = g.x * bf2f(u[j].x) + g.y * bf2f(u[j].y) +
                  g.z * bf2f(u[j].z) + g.w * bf2f(u[j].w);
        v += __shfl_down(v, 16, 32);
        v += __shfl_down(v, 8, 32);
        v += __shfl_down(v, 4, 32);
        v += __shfl_down(v, 2, 32);
        v += __shfl_down(v, 1, 32);
        corr[j] = v;
    }

    if (sub == 0 && n < N) {
        float mx = -1e30f;
        #pragma unroll
        for (int j = 0; j < 25; ++j) mx = fmaxf(mx, corr[j]);
        float sum = 0.f;
        #pragma unroll
        for (int j = 0; j < 25; ++j) {
            const float e = __expf(corr[j] - mx);
            corr[j] = e;
            sum += e;
        }
        const float inv = 1.f / sum;
        float ox = 0.f, oy = 0.f;
        #pragma unroll
        for (int j = 0; j < 25; ++j) {
            const float w = corr[j] * inv;
            ox += w * (float)(j % WIN - HALFW);
            oy += w * (float)(j / WIN - HALFW);
        }
        if (!valid) { ox = 0.f; oy = 0.f; }
        const float sf = (float)stride;
        float2 p0, p1;
        p0.x = m0.x * sf + half_s;
        p0.y = m0.y * sf + half_s;
        p1.x = m1.x * sf + half_s + ox * scale;
        p1.y = m1.y * sf + half_s + oy * scale;
        *(float2*)&out[2 * n] = p0;
        *(float2*)&out[2 * N + 2 * n] = p1;
    }
}

// Fallback (no workspace for ft): round-1 style direct fp32 path.
__global__ __launch_bounds__(CCH) void fr_refine_fb(
    const float* __restrict__ mk0, const float* __restrict__ mk1,
    const float* __restrict__ feat0, const float* __restrict__ feat1,
    const float* __restrict__ Mv, const int* __restrict__ stride_p,
    float* __restrict__ out, int N, int H, int W) {

    const int n = blockIdx.x;
    const int t = threadIdx.x;
    const long HW = (long)H * W;

    const int stride = *stride_p;
    const int fine_ratio = stride >> 1;
    const float frf = (float)fine_ratio;
    const float scale = (float)(stride / fine_ratio);
    const float half_s = (float)(stride >> 1);

    const float m0x = mk0[2 * n], m0y = mk0[2 * n + 1];
    const float m1x = mk1[2 * n], m1y = mk1[2 * n + 1];

    const int cx0 = (int)(m0x * frf), cy0 = (int)(m0y * frf);
    const int cx1 = (int)(m1x * frf), cy1 = (int)(m1y * frf);

    const bool valid =
        (cx0 >= HALFW) && (cx0 + HALFW < W) && (cy0 >= HALFW) && (cy0 + HALFW < H) &&
        (cx1 >= HALFW) && (cx1 + HALFW < W) && (cy1 >= HALFW) && (cy1 + HALFW < H);

    const int cx0c = min(max(cx0, HALFW), W - 1 - HALFW);
    const int cy0c = min(max(cy0, HALFW), H - 1 - HALFW);
    const int cx1c = min(max(cx1, HALFW), W - 1 - HALFW);
    const int cy1c = min(max(cy1, HALFW), H - 1 - HALFW);

    __shared__ float sh_x0[CCH];
    __shared__ float red[2 * 25];

    sh_x0[t] = feat0[(long)t * HW + (long)cy0c * W + cx0c];
    __syncthreads();

    float g = Mv[CCH * CCH + t];
    #pragma unroll 8
    for (int c = 0; c < CCH; ++c) g = fmaf(Mv[c * CCH + t], sh_x0[c], g);

    const float* f1b = feat1 + (long)t * HW + (long)(cy1c - HALFW) * W + (cx1c - HALFW);
    float prod[25];
    #pragma unroll
    for (int dy = 0; dy < WIN; ++dy)
        #pragma unroll
        for (int dx = 0; dx < WIN; ++dx)
            prod[dy * WIN + dx] = g * f1b[(long)dy * W + dx];

    const int lane = t & 63;
    const int wv = t >> 6;
    #pragma unroll
    for (int j = 0; j < 25; ++j) {
        float v = prod[j];
        v += __shfl_down(v, 32);
        v += __shfl_down(v, 16);
        v += __shfl_down(v, 8);
        v += __shfl_down(v, 4);
        v += __shfl_down(v, 2);
        v += __shfl_down(v, 1);
        if (lane == 0) red[wv * 25 + j] = v;
    }
    __syncthreads();

    if (t == 0) {
        float corr[25];
        float mx = -1e30f;
        #pragma unroll
        for (int j = 0; j < 25; ++j) { corr[j] = red[j] + red[25 + j]; mx = fmaxf(mx, corr[j]); }
        float sum = 0.f;
        #pragma unroll
        for (int j = 0; j < 25; ++j) { const float e = __expf(corr[j] - mx); corr[j] = e; sum += e; }
        const float inv = 1.f / sum;
        float ox = 0.f, oy = 0.f;
        #pragma unroll
        for (int j = 0; j < 25; ++j) {
            const float w = corr[j] * inv;
            ox += w * (float)(j % WIN - HALFW);
            oy += w * (float)(j / WIN - HALFW);
        }
        if (!valid) { ox = 0.f; oy = 0.f; }
        const float sf = (float)stride;
        out[2 * N + 2 * n]     = m1x * sf + half_s + ox * scale;
        out[2 * N + 2 * n + 1] = m1y * sf + half_s + oy * scale;
        out[2 * n]     = m0x * sf + half_s;
        out[2 * n + 1] = m0y * sf + half_s;
    }
}

extern "C" void kernel_launch(void* const* d_in, const int* in_sizes, int n_in,
                              void* d_out, int out_size, void* d_ws, size_t ws_size,
                              hipStream_t stream) {
    const float* mk0 = (const float*)d_in[0];
    const float* mk1 = (const float*)d_in[1];
    const float* f0  = (const float*)d_in[2];
    const float* f1  = (const float*)d_in[3];
    const float* pw  = (const float*)d_in[4];
    const float* pb  = (const float*)d_in[5];
    const int*   sp  = (const int*)d_in[6];

    const int N = in_sizes[0] / 2;              // 20000
    const long HW = (long)in_sizes[2] / CCH;    // 409600
    const int Wf = (int)(sqrt((double)HW) + 0.5);
    const int Hf = (int)(HW / Wf);

    const size_t mv_bytes = (size_t)(CCH * CCH + CCH) * sizeof(float);   // 66048 (16B-mult)
    const size_t ft_bytes = (size_t)HW * CCH * sizeof(unsigned short);   // ~105 MB
    const bool use_ft = (ws_size >= mv_bytes + ft_bytes);

    float* Mv = (float*)d_ws;
    unsigned short* ft = (unsigned short*)((char*)d_ws + mv_bytes);

    fr_precompute<<<CCH + 1, CCH, 0, stream>>>(pw, pb, Mv);

    if (use_ft) {
        fr_transpose_bf16<<<(int)(HW / 64), 256, 0, stream>>>(f1, ft, HW);
        fr_refine2<<<(N + 7) / 8, 256, 0, stream>>>(mk0, mk1, f0, ft, Mv, sp,
                                                    (float*)d_out, N, Hf, Wf);
    } else {
        fr_refine_fb<<<N, CCH, 0, stream>>>(mk0, mk1, f0, f1, Mv, sp,
                                            (float*)d_out, N, Hf, Wf);
    }
}